// Round 12
// baseline (282.980 us; speedup 1.0000x reference)
//
#include <hip/hip_runtime.h>
#include <hip/hip_bf16.h>
#include <cmath>

#define NB 32
#define NS 4096
#define NK 1024
#define ND 512
#define WSTRIDE 1536   // ENC2 + DEC
#define NTO 16         // outer K-steps (BK=64; two 32-k MFMA sub-phases each)

using bf16x8 = __attribute__((ext_vector_type(8))) __bf16;
using u16x8  = __attribute__((ext_vector_type(8))) unsigned short;
using f32x4  = __attribute__((ext_vector_type(4))) float;
typedef unsigned short u16;

__device__ inline u16 f2b(float x) {
    __hip_bfloat16 h = __float2bfloat16(x);
    u16 u; __builtin_memcpy(&u, &h, 2); return u;
}

__device__ inline float fast_tanh(float x) {
    float xc = fminf(fmaxf(x, -10.f), 10.f);
    float e = __expf(2.f * xc);
    return (e - 1.f) / (e + 1.f);
}

// ---------------------------------------------------------------------------
// Kernel 0: pack Wc = W_attn[:, 512:] -> bf16 in MFMA-FRAGMENT order so the
// GEMM loads B fragments directly L2->registers (no LDS for B):
//   fragment (ks, n6, c): 1KB = lane*16B, lane = kk*16 + rr,
//   content = Wc[d = n6*64 + c*16 + rr][k = ks*32 + kk*8 + j]  (j = 0..7)
// This is byte-identical content to what the old LDS path delivered per lane.
__global__ void pack_wc_kernel(const float* __restrict__ W, u16* __restrict__ wcb) {
    int idx = blockIdx.x * 256 + threadIdx.x;   // 512*1024 elements
    int d = idx >> 10, k = idx & 1023;
    float val = W[(size_t)d * WSTRIDE + ND + k];
    int ks = k >> 5, kk = (k >> 3) & 3, j = k & 7;
    int n6 = d >> 6, c = (d >> 4) & 3, rr = d & 15;
    int frag = (((ks << 3) + n6) << 2) + c;     // 0..1023
    wcb[frag * 512 + ((kk << 4) + rr) * 8 + j] = f2b(val);
}

// ---------------------------------------------------------------------------
// Kernel 1: h_proj[b][d] = bias[d] + sum_k hidden[b][k] * W_attn[d][k]  (f32 exact)
__global__ void hproj_kernel(const float* __restrict__ hidden, const float* __restrict__ W,
                             const float* __restrict__ bias, float* __restrict__ hp) {
    int b = blockIdx.x, d = threadIdx.x;   // 512 threads
    __shared__ float sh[ND];
    sh[d] = hidden[b * ND + d];
    __syncthreads();
    const float4* wr = (const float4*)(W + (size_t)d * WSTRIDE);
    float acc = bias[d];
#pragma unroll 8
    for (int k = 0; k < ND / 4; k++) {
        float4 w4 = wr[k];
        acc += w4.x * sh[4 * k] + w4.y * sh[4 * k + 1] + w4.z * sh[4 * k + 2] + w4.w * sh[4 * k + 3];
    }
    hp[b * ND + d] = acc;
}

// ---------------------------------------------------------------------------
// Kernel 2: fused c_proj GEMM (bf16 MFMA) + tanh + dot-v -> scores
// Block 128x512, 1024 threads / 16 waves as 2M x 8N, wave tile 64x64.
// B: DIRECT L2->register fragment loads (1KB coalesced, L1-hot) — no LDS,
//    no DMA, no block coupling for B.
// A: LDS-staged at BK=64 (2 x 16KB double buffer), XOR-swizzled granules,
//    ONE barrier per 64-k (16 total). Barrier region contains only the A
//    ds_write; B flows freely per-wave.
// FIFO per wave per T: entry va=A(T+1) (loads possibly in flight);
//   sub0: +4 B -> vmcnt(4) drains A; CVT/ds_write; issue A(T+2); vmcnt(2)
//         +lgkm(0) -> B landed, A(T+2) stays in flight; 16 MFMA.
//   sub1: +4 B -> vmcnt(0)+lgkm(0) (A(T+2) long-issued, ~free); 16 MFMA;
//         barrier.
__global__ __launch_bounds__(1024, 4)
void fused_scores_kernel(const float* __restrict__ ctx, const u16* __restrict__ wcb,
                         const float* __restrict__ hp, const float* __restrict__ vvec,
                         float* __restrict__ scores) {
    __shared__ __align__(16) char lA[2][128 * 128];  // 2 x 16 KB (BK=64 bf16)

    const int tid = threadIdx.x;
    const int blk = blockIdx.x;             // 1024 blocks
    const int b  = blk >> 5;                // 32 M-tiles per batch
    const int s0 = (blk & 31) << 7;

    const int lane = tid & 63, wid = tid >> 6;      // wid 0..15
    const int l15 = lane & 15, l4 = lane >> 4;
    const int wm = wid >> 3, wn = wid & 7;          // 2M x 8N

    // A staging: thread -> row = tid>>3 (0..127), q = tid&7; 32B contiguous
    // (k = q*8..q*8+7 f32) -> one swizzled 16B granule in a 128B LDS row.
    const int srow = tid >> 3, q = tid & 7;
    const float4* asrc = (const float4*)(ctx + (size_t)b * NS * NK + (size_t)(s0 + srow) * NK);
    const int awbyte = (srow << 7) + ((q ^ (srow & 7)) << 4);

    // A fragment offsets (k-half 0); half 1 = ^64 (XOR family flips bit 6)
    int aoff[4];
#pragma unroll
    for (int r = 0; r < 4; r++) {
        int row = (wm << 6) + (r << 4) + l15;
        aoff[r] = (row << 7) + ((l4 ^ (row & 7)) << 4);
    }

    // B fragment base: frag(ks, wn, c) at bytes ks*32768 + wn*4096 + c*1024
    const char* bptr = (const char*)wcb + (wn << 12) + (lane << 4);

    f32x4 acc[4][4];
    f32x4 zero = {0.f, 0.f, 0.f, 0.f};
#pragma unroll
    for (int r = 0; r < 4; r++)
#pragma unroll
        for (int c = 0; c < 4; c++) acc[r][c] = zero;

    float4 va0, va1;

#define CVT_WRITE_A(buf)                                                             \
    {                                                                                \
        u16x8 a8;                                                                    \
        a8[0] = f2b(va0.x); a8[1] = f2b(va0.y); a8[2] = f2b(va0.z); a8[3] = f2b(va0.w); \
        a8[4] = f2b(va1.x); a8[5] = f2b(va1.y); a8[6] = f2b(va1.z); a8[7] = f2b(va1.w); \
        *(u16x8*)(&lA[buf][awbyte]) = a8;                                            \
    }

#define MFMA16(afv, bfv)                                                             \
    {                                                                                \
        __builtin_amdgcn_s_setprio(1);                                               \
        _Pragma("unroll")                                                            \
        for (int r = 0; r < 4; r++)                                                  \
            _Pragma("unroll")                                                        \
            for (int c = 0; c < 4; c++)                                              \
                acc[r][c] = __builtin_amdgcn_mfma_f32_16x16x32_bf16(                 \
                    afv[r], bfv[c], acc[r][c], 0, 0, 0);                             \
        __builtin_amdgcn_s_setprio(0);                                               \
    }

    // ---- prologue: stage A tile 0, prefetch A(1) regs ----
    va0 = asrc[2 * q];
    va1 = asrc[2 * q + 1];
    asm volatile("s_waitcnt vmcnt(0)" ::: "memory");
    CVT_WRITE_A(0);
    va0 = asrc[16 + 2 * q];            // A(1) in flight
    va1 = asrc[16 + 2 * q + 1];
    asm volatile("s_waitcnt lgkmcnt(0)" ::: "memory");
    __builtin_amdgcn_s_barrier();
    __builtin_amdgcn_sched_barrier(0);

    // ---- main loop: one barrier per 64-k tile ----
#pragma unroll 2
    for (int T = 0; T < NTO; T++) {
        const int cur = T & 1, nxt = cur ^ 1;
        const int tA = (T + 2 < NTO) ? T + 2 : NTO - 1;   // clamp: uniform counts

        bf16x8 af[4], bfr[4];

        // ===== sub0: k-half 0, B chunk ks=2T =====
#pragma unroll
        for (int c = 0; c < 4; c++)
            bfr[c] = *(const bf16x8*)(bptr + (T << 16) + (c << 10));
#pragma unroll
        for (int r = 0; r < 4; r++)
            af[r] = *(const bf16x8*)(&lA[cur][aoff[r]]);
        asm volatile("s_waitcnt vmcnt(4)" ::: "memory");   // A(T+1) regs landed
        CVT_WRITE_A(nxt);
        va0 = asrc[tA * 16 + 2 * q];                       // issue A(T+2)
        va1 = asrc[tA * 16 + 2 * q + 1];
        asm volatile("s_waitcnt vmcnt(2) lgkmcnt(0)" ::: "memory"); // B landed, A in flight
        MFMA16(af, bfr);

        // ===== sub1: k-half 1, B chunk ks=2T+1 =====
#pragma unroll
        for (int c = 0; c < 4; c++)
            bfr[c] = *(const bf16x8*)(bptr + (T << 16) + 32768 + (c << 10));
#pragma unroll
        for (int r = 0; r < 4; r++)
            af[r] = *(const bf16x8*)(&lA[cur][aoff[r] ^ 64]);
        asm volatile("s_waitcnt vmcnt(0) lgkmcnt(0)" ::: "memory"); // A(T+2) ~done anyway
        MFMA16(af, bfr);
        __builtin_amdgcn_s_barrier();
        __builtin_amdgcn_sched_barrier(0);
    }

    // --- epilogue: tanh(c_proj + h_proj) . v , reduce over d ---
    // C/D: col = lane&15 (d), row = l4*4 + i (s within frag)
    const float* hpb = hp + b * ND;
    float part[4][4];
#pragma unroll
    for (int r = 0; r < 4; r++)
#pragma unroll
        for (int i = 0; i < 4; i++) part[r][i] = 0.f;

#pragma unroll
    for (int c = 0; c < 4; c++) {
        int d = (wn << 6) + (c << 4) + l15;
        float hpv = hpb[d], vv = vvec[d];
#pragma unroll
        for (int r = 0; r < 4; r++)
#pragma unroll
            for (int i = 0; i < 4; i++)
                part[r][i] += fast_tanh(acc[r][c][i] + hpv) * vv;
    }

    float* sc = (float*)lA;   // 8 x 128 floats = 4 KB, aliases lA (reads done)
#pragma unroll
    for (int r = 0; r < 4; r++) {
#pragma unroll
        for (int i = 0; i < 4; i++) {
            float p = part[r][i];
            p += __shfl_xor(p, 1); p += __shfl_xor(p, 2);
            p += __shfl_xor(p, 4); p += __shfl_xor(p, 8);
            // local s-row = wm*64 + r*16 + l4*4 + i
            if (l15 == 0) sc[(wn << 7) + (wm << 6) + (r << 4) + (l4 << 2) + i] = p;
        }
    }
    __syncthreads();
    if (tid < 128) {
        float s = 0.f;
#pragma unroll
        for (int w = 0; w < 8; w++) s += sc[(w << 7) + tid];
        scores[(size_t)b * NS + s0 + tid] = s;
    }
}

// ---------------------------------------------------------------------------
// Kernel 3: masked softmax over S per batch row, f32 output
__global__ void softmax_kernel(const float* __restrict__ scores, const int* __restrict__ mask,
                               float* __restrict__ out) {
    int b = blockIdx.x, tid = threadIdx.x;   // 256 threads, 16 elems each
    __shared__ float red[256];
    float loc[16];
    float mx = -INFINITY;
#pragma unroll
    for (int i = 0; i < 16; i++) {
        int idx = i * 256 + tid;
        float s = scores[b * NS + idx];
        if (mask[b * NS + idx] == 0) s = -INFINITY;
        loc[i] = s;
        mx = fmaxf(mx, s);
    }
    red[tid] = mx; __syncthreads();
    for (int off = 128; off; off >>= 1) { if (tid < off) red[tid] = fmaxf(red[tid], red[tid + off]); __syncthreads(); }
    mx = red[0]; __syncthreads();
    float sum = 0.f;
#pragma unroll
    for (int i = 0; i < 16; i++) { float e = __expf(loc[i] - mx); loc[i] = e; sum += e; }
    red[tid] = sum; __syncthreads();
    for (int off = 128; off; off >>= 1) { if (tid < off) red[tid] += red[tid + off]; __syncthreads(); }
    float inv = 1.f / red[0];
#pragma unroll
    for (int i = 0; i < 16; i++) out[b * NS + i * 256 + tid] = loc[i] * inv;
}

// ---------------------------------------------------------------------------
extern "C" void kernel_launch(void* const* d_in, const int* in_sizes, int n_in,
                              void* d_out, int out_size, void* d_ws, size_t ws_size,
                              hipStream_t stream) {
    const float* hidden  = (const float*)d_in[0];
    const float* context = (const float*)d_in[1];
    const int*   mask    = (const int*)d_in[2];
    const float* W_attn  = (const float*)d_in[3];
    const float* b_attn  = (const float*)d_in[4];
    const float* v       = (const float*)d_in[5];
    float* out           = (float*)d_out;

    char* ws = (char*)d_ws;
    u16*   wcb    = (u16*)ws;                   // 1 MB
    float* hp     = (float*)(ws + (1 << 20));   // 64 KB
    float* scores = (float*)(ws + (1 << 20) + (64 << 10));  // 512 KB

    pack_wc_kernel<<<2048, 256, 0, stream>>>(W_attn, wcb);
    hproj_kernel<<<NB, ND, 0, stream>>>(hidden, W_attn, b_attn, hp);
    fused_scores_kernel<<<NB * 32, 1024, 0, stream>>>(context, wcb, hp, v, scores);
    softmax_kernel<<<NB, 256, 0, stream>>>(scores, mask, out);
}

// Round 13
// 255.719 us; speedup vs baseline: 1.1066x; 1.1066x over previous
//
#include <hip/hip_runtime.h>
#include <hip/hip_bf16.h>
#include <cmath>

#define NB 32
#define NS 4096
#define NK 1024
#define ND 512
#define WSTRIDE 1536   // ENC2 + DEC
#define NT 32          // K-steps (BK=32)

using bf16x8 = __attribute__((ext_vector_type(8))) __bf16;
using f32x4  = __attribute__((ext_vector_type(4))) float;
typedef unsigned short u16;

__device__ inline u16 f2b(float x) {
    __hip_bfloat16 h = __float2bfloat16(x);
    u16 u; __builtin_memcpy(&u, &h, 2); return u;
}

__device__ inline float fast_tanh(float x) {
    float xc = fminf(fmaxf(x, -10.f), 10.f);
    float e = __expf(2.f * xc);
    return (e - 1.f) / (e + 1.f);
}

// ---------------------------------------------------------------------------
// Kernel 0 (merged prep): blocks 0..2047 pack Wc -> bf16 pre-swizzled;
// blocks 2048..2111 compute h_proj (f32 exact).
// Pack layout (64B LDS rows): element (R, k=ks*32+S*8+j) at granule
// g = R*4 + (S ^ ((R>>1)&3)) of chunk ks  (conflict-free; r9: conflicts = 0).
__global__ void prep_kernel(const float* __restrict__ W, const float* __restrict__ hidden,
                            const float* __restrict__ bias, u16* __restrict__ wcb,
                            float* __restrict__ hp) {
    const int blk = blockIdx.x, tid = threadIdx.x;   // 256 threads
    if (blk < 2048) {
        int idx = blk * 256 + tid;                   // 512*1024 elements
        int R = idx >> 10, k = idx & 1023;
        float val = W[(size_t)R * WSTRIDE + ND + k];
        int ks = k >> 5, S = (k >> 3) & 3, j = k & 7;
        int g = (R << 2) + (S ^ ((R >> 1) & 3));     // granule 0..2047 (bijective)
        wcb[(ks << 14) + (g << 3) + j] = f2b(val);
    } else {
        int g = blk - 2048;                          // 64 blocks: b = g>>1, half = g&1
        int b = g >> 1;
        int d = ((g & 1) << 8) + tid;
        __shared__ float sh[ND];
        sh[tid] = hidden[b * ND + tid];
        sh[256 + tid] = hidden[b * ND + 256 + tid];
        __syncthreads();
        const float4* wr = (const float4*)(W + (size_t)d * WSTRIDE);
        float acc = bias[d];
#pragma unroll 8
        for (int k = 0; k < ND / 4; k++) {
            float4 w4 = wr[k];
            acc += w4.x * sh[4 * k] + w4.y * sh[4 * k + 1] + w4.z * sh[4 * k + 2] + w4.w * sh[4 * k + 3];
        }
        hp[b * ND + d] = acc;
    }
}

// ---------------------------------------------------------------------------
// Kernel 1: fused c_proj GEMM (bf16 MFMA) + tanh + dot-v -> scores
// Block tile 128x512, BK=32, 1024 threads / 16 waves as 2M x 8N ->
// wave tile 64x64 (acc[4][4]=64 VGPR), LDS 80 KiB -> 2 blocks/CU.
// ROUND-13 CHANGE (T14 issue-early/write-late): per iteration the MFMA
// cluster runs FIRST (operands already resident from last iter's barrier);
// the A-HBM drain + cvt/ds_write + next-A issue follow, hidden under the
// cluster's MFMA issue. FIFO per wave: entry = A(t+1)x1; +2 B-DMA -> 3;
// MFMA; vmcnt(2) drains A(t+1) (~0 stall, landed long ago); cvt+write;
// issue A(t+2); vmcnt(1)+lgkm(0) drains B(t+1) only; barrier. Never 0.
__global__ __launch_bounds__(1024, 4)
void fused_scores_kernel(const float* __restrict__ ctx, const u16* __restrict__ wcb,
                         const float* __restrict__ hp, const float* __restrict__ vvec,
                         float* __restrict__ scores) {
    __shared__ __align__(16) char lA[2][128 * 64];   // 2 x 8 KB (BK=32 bf16)
    __shared__ __align__(16) char lB[2][512 * 64];   // 2 x 32 KB (BK=32 bf16)
    // total 80 KiB exactly; epilogue scratch aliases lA.

    const int tid = threadIdx.x;
    const int blk = blockIdx.x;             // 1024 blocks
    const int b  = blk >> 5;                // 32 M-tiles per batch
    const int s0 = (blk & 31) << 7;

    const int lane = tid & 63, wid = tid >> 6;      // wid 0..15
    const int l15 = lane & 15, l4 = lane >> 4;
    const int wm = wid >> 3, wn = wid & 7;          // 2M x 8N

    // A staging: thread -> row = tid>>3 (0..127), q = tid&7; one float4
    // (k = q*4..q*4+3) -> 4 bf16 = 8B LDS write at the swizzled granule-half.
    const int srow = tid >> 3, q = tid & 7;
    const float4* asrc = (const float4*)(ctx + (size_t)b * NS * NK + (size_t)(s0 + srow) * NK);
    const int awbyte = (srow << 6) + ((((q >> 1) ^ ((srow >> 1) & 3))) << 4) + ((q & 1) << 3);

    // fragment LDS byte offsets (loop-invariant); same swizzle family for A & B
    int aoff[4], boff[4];
#pragma unroll
    for (int r = 0; r < 4; r++) {
        int row = (wm << 6) + (r << 4) + l15;             // wave owns 64 M rows
        aoff[r] = (row << 6) + ((l4 ^ ((row >> 1) & 3)) << 4);
    }
#pragma unroll
    for (int c = 0; c < 4; c++) {
        int row = (wn << 6) + (c << 4) + l15;             // wave owns 64 d-cols
        boff[c] = (row << 6) + ((l4 ^ ((row >> 1) & 3)) << 4);
    }

    f32x4 acc[4][4];
    f32x4 zero = {0.f, 0.f, 0.f, 0.f};
#pragma unroll
    for (int r = 0; r < 4; r++)
#pragma unroll
        for (int c = 0; c < 4; c++) acc[r][c] = zero;

    const char* wcb_bytes = (const char*)wcb;
    float4 va;

#define STAGE_B_DMA(chunk, buf)                                                      \
    _Pragma("unroll")                                                                \
    for (int i = 0; i < 2; i++) {                                                    \
        const char* src = wcb_bytes + ((size_t)(chunk) << 15)                        \
                          + (((((wid << 1) + i) << 6) + lane) << 4);                 \
        __builtin_amdgcn_global_load_lds(                                            \
            (const __attribute__((address_space(1))) void*)src,                      \
            (__attribute__((address_space(3))) void*)(&lB[buf][((wid << 1) + i) << 10]), \
            16, 0, 0);                                                               \
    }

#define CVT_WRITE_A(buf)                                                             \
    {                                                                                \
        ushort4 a4;                                                                  \
        a4.x = f2b(va.x); a4.y = f2b(va.y); a4.z = f2b(va.z); a4.w = f2b(va.w);      \
        *(ushort4*)(&lA[buf][awbyte]) = a4;                                          \
    }

#define MFMA_CLUSTER(abuf, bbuf)                                                     \
    {                                                                                \
        bf16x8 af[4], bfr[4];                                                        \
        _Pragma("unroll")                                                            \
        for (int r = 0; r < 4; r++) af[r] = *(const bf16x8*)(&lA[abuf][aoff[r]]);    \
        _Pragma("unroll")                                                            \
        for (int c = 0; c < 4; c++) bfr[c] = *(const bf16x8*)(&lB[bbuf][boff[c]]);   \
        asm volatile("s_waitcnt lgkmcnt(0)" ::: "memory");                           \
        __builtin_amdgcn_sched_barrier(0);                                           \
        __builtin_amdgcn_s_setprio(1);                                               \
        _Pragma("unroll")                                                            \
        for (int r = 0; r < 4; r++)                                                  \
            _Pragma("unroll")                                                        \
            for (int c = 0; c < 4; c++)                                              \
                acc[r][c] = __builtin_amdgcn_mfma_f32_16x16x32_bf16(                 \
                    af[r], bfr[c], acc[r][c], 0, 0, 0);                              \
        __builtin_amdgcn_s_setprio(0);                                               \
    }

    // ---- prologue: stage B chunk 0 + A tile 0, prefetch A(1) regs ----
    STAGE_B_DMA(0, 0);
    va = asrc[q];
    asm volatile("s_waitcnt vmcnt(0)" ::: "memory");
    CVT_WRITE_A(0);
    va = asrc[8 + q];                  // A(1) in flight
    asm volatile("s_waitcnt lgkmcnt(0)" ::: "memory");
    __builtin_amdgcn_s_barrier();
    __builtin_amdgcn_sched_barrier(0);

    // ---- main loop: compute-first, stage-late (T14) ----
#pragma unroll 2
    for (int t = 0; t < NT; t++) {
        const int cur = t & 1, nxt = cur ^ 1;
        const int cB = (t + 1 < NT) ? t + 1 : NT - 1;   // clamp keeps counts uniform
        const int tA = (t + 2 < NT) ? t + 2 : NT - 1;

        STAGE_B_DMA(cB, nxt);                              // +2 -> 3 outstanding
        MFMA_CLUSTER(cur, cur);                            // compute on resident bufs
        asm volatile("s_waitcnt vmcnt(2)" ::: "memory");   // A(t+1) reg (landed long ago)
        CVT_WRITE_A(nxt);
        va = asrc[(tA << 3) + q];                          // A(t+2) in flight
        asm volatile("s_waitcnt vmcnt(1) lgkmcnt(0)" ::: "memory"); // drain B(t+1), keep A
        __builtin_amdgcn_s_barrier();
        __builtin_amdgcn_sched_barrier(0);
    }

    // --- epilogue: tanh(c_proj + h_proj) . v , reduce over d ---
    // C/D: col = lane&15 (d), row = l4*4 + i (s within frag)
    const float* hpb = hp + b * ND;
    float part[4][4];
#pragma unroll
    for (int r = 0; r < 4; r++)
#pragma unroll
        for (int i = 0; i < 4; i++) part[r][i] = 0.f;

#pragma unroll
    for (int c = 0; c < 4; c++) {
        int d = (wn << 6) + (c << 4) + l15;
        float hpv = hpb[d], vv = vvec[d];
#pragma unroll
        for (int r = 0; r < 4; r++)
#pragma unroll
            for (int i = 0; i < 4; i++)
                part[r][i] += fast_tanh(acc[r][c][i] + hpv) * vv;
    }

    float* sc = (float*)lA;   // 8 x 128 floats = 4 KB, aliases lA (reads done)
#pragma unroll
    for (int r = 0; r < 4; r++) {
#pragma unroll
        for (int i = 0; i < 4; i++) {
            float p = part[r][i];
            p += __shfl_xor(p, 1); p += __shfl_xor(p, 2);
            p += __shfl_xor(p, 4); p += __shfl_xor(p, 8);
            // local s-row = wm*64 + r*16 + l4*4 + i
            if (l15 == 0) sc[(wn << 7) + (wm << 6) + (r << 4) + (l4 << 2) + i] = p;
        }
    }
    __syncthreads();
    if (tid < 128) {
        float s = 0.f;
#pragma unroll
        for (int w = 0; w < 8; w++) s += sc[(w << 7) + tid];
        scores[(size_t)b * NS + s0 + tid] = s;
    }
}

// ---------------------------------------------------------------------------
// Kernel 2: masked softmax over S per batch row, f32 output
__global__ void softmax_kernel(const float* __restrict__ scores, const int* __restrict__ mask,
                               float* __restrict__ out) {
    int b = blockIdx.x, tid = threadIdx.x;   // 256 threads, 16 elems each
    __shared__ float red[256];
    float loc[16];
    float mx = -INFINITY;
#pragma unroll
    for (int i = 0; i < 16; i++) {
        int idx = i * 256 + tid;
        float s = scores[b * NS + idx];
        if (mask[b * NS + idx] == 0) s = -INFINITY;
        loc[i] = s;
        mx = fmaxf(mx, s);
    }
    red[tid] = mx; __syncthreads();
    for (int off = 128; off; off >>= 1) { if (tid < off) red[tid] = fmaxf(red[tid], red[tid + off]); __syncthreads(); }
    mx = red[0]; __syncthreads();
    float sum = 0.f;
#pragma unroll
    for (int i = 0; i < 16; i++) { float e = __expf(loc[i] - mx); loc[i] = e; sum += e; }
    red[tid] = sum; __syncthreads();
    for (int off = 128; off; off >>= 1) { if (tid < off) red[tid] += red[tid + off]; __syncthreads(); }
    float inv = 1.f / red[0];
#pragma unroll
    for (int i = 0; i < 16; i++) out[b * NS + i * 256 + tid] = loc[i] * inv;
}

// ---------------------------------------------------------------------------
extern "C" void kernel_launch(void* const* d_in, const int* in_sizes, int n_in,
                              void* d_out, int out_size, void* d_ws, size_t ws_size,
                              hipStream_t stream) {
    const float* hidden  = (const float*)d_in[0];
    const float* context = (const float*)d_in[1];
    const int*   mask    = (const int*)d_in[2];
    const float* W_attn  = (const float*)d_in[3];
    const float* b_attn  = (const float*)d_in[4];
    const float* v       = (const float*)d_in[5];
    float* out           = (float*)d_out;

    char* ws = (char*)d_ws;
    u16*   wcb    = (u16*)ws;                   // 1 MB
    float* hp     = (float*)(ws + (1 << 20));   // 64 KB
    float* scores = (float*)(ws + (1 << 20) + (64 << 10));  // 512 KB

    prep_kernel<<<2112, 256, 0, stream>>>(W_attn, hidden, b_attn, wcb, hp);
    fused_scores_kernel<<<NB * 32, 1024, 0, stream>>>(context, wcb, hp, v, scores);
    softmax_kernel<<<NB, 256, 0, stream>>>(scores, mask, out);
}